// Round 1
// baseline (290.370 us; speedup 1.0000x reference)
//
#include <hip/hip_runtime.h>
#include <hip/hip_bf16.h>

// NSA compression attention forward, MI355X/gfx950.
// Z=4 H=16 G=4 S=4096 BLOCK=32 NB=128 DQK=DV=128, fp32 in/out.
// Strategy: per-WG tile = one (z,h) x 128 queries vs all 128 compressed blocks.
// K and V^T staged in LDS as bf16 (32 KB each, 64 KB total -> 2 WG/CU).
// S = Q*K^T and O = P*V via mfma_f32_16x16x32_bf16. P reuses K's LDS buffer.

#define Zc 4
#define Hc 16
#define Gc 4
#define Sc 4096
#define NBc 128
#define Dc 128

typedef __attribute__((ext_vector_type(8))) short short8;   // 8 bf16 (4 VGPRs)
typedef __attribute__((ext_vector_type(4))) float float4v;  // 4 fp32

__device__ inline short f2bf(float f) {
    union { float f; unsigned u; } x; x.f = f;
    unsigned r = (x.u + 0x7fffu + ((x.u >> 16) & 1u)) >> 16;   // RNE
    return (short)r;
}

__global__ __launch_bounds__(256, 2)
void nsa_fwd(const float* __restrict__ q, const float* __restrict__ kb,
             const float* __restrict__ vb, float* __restrict__ out) {
    // LDS: K [blk][d] bf16 (later reused as P [row][blk]); Vt [dv][blk] bf16.
    __shared__ __align__(16) short Ksh[NBc * Dc];   // 32 KB
    __shared__ __align__(16) short Vt[Dc * NBc];    // 32 KB

    const int m0   = blockIdx.x * 128;    // query tile start
    const int h    = blockIdx.y;
    const int z    = blockIdx.z;
    const int g    = h >> 2;              // H/G = 4
    const int tid  = threadIdx.x;
    const int wave = tid >> 6;
    const int lane = tid & 63;
    const int l16  = lane & 15;
    const int quad = lane >> 4;

    // ---- stage K as bf16 (coalesced: 32 B/thread/iter) ----
    const float* ksrc = kb + ((size_t)(z * Gc + g)) * NBc * Dc;
    for (int i = tid; i < NBc * Dc / 8; i += 256) {
        const float4v* p = (const float4v*)(ksrc + (size_t)i * 8);
        float4v f0 = p[0], f1 = p[1];
        short8 o;
        o[0]=f2bf(f0[0]); o[1]=f2bf(f0[1]); o[2]=f2bf(f0[2]); o[3]=f2bf(f0[3]);
        o[4]=f2bf(f1[0]); o[5]=f2bf(f1[1]); o[6]=f2bf(f1[2]); o[7]=f2bf(f1[3]);
        ((short8*)Ksh)[i] = o;
    }
    // ---- stage V transposed: Vt[dv][blk] ----
    const float* vsrc = vb + ((size_t)(z * Gc + g)) * NBc * Dc;
    for (int i = tid; i < NBc * Dc / 4; i += 256) {
        int c = i >> 7;        // dv chunk (4 elems), 0..31
        int n = i & 127;       // block index (consecutive lanes -> consecutive n)
        float4v f = *(const float4v*)(vsrc + (size_t)n * Dc + c * 4);
        Vt[(c * 4 + 0) * NBc + n] = f2bf(f[0]);
        Vt[(c * 4 + 1) * NBc + n] = f2bf(f[1]);
        Vt[(c * 4 + 2) * NBc + n] = f2bf(f[2]);
        Vt[(c * 4 + 3) * NBc + n] = f2bf(f[3]);
    }
    __syncthreads();

    // ---- S = (Q*scale) * K^T ----
    const float sm_scale = 0.08838834764831845f;   // 1/sqrt(128)
    const int row_base = wave * 32;                // this wave's 32-row strip
    const float* qtile = q + (((size_t)(z * Hc + h)) * Sc + m0) * Dc;

    float4v acc[2][8];
    #pragma unroll
    for (int t = 0; t < 2; t++)
        #pragma unroll
        for (int c = 0; c < 8; c++) acc[t][c] = (float4v)0.f;

    #pragma unroll
    for (int kbi = 0; kbi < 4; kbi++) {
        const int d0 = kbi * 32 + quad * 8;
        short8 afrag[2];
        #pragma unroll
        for (int t = 0; t < 2; t++) {
            const float* src = qtile + (size_t)(row_base + t * 16 + l16) * Dc + d0;
            float4v f0 = *(const float4v*)src;
            float4v f1 = *(const float4v*)(src + 4);
            short8 a;
            a[0]=f2bf(f0[0]*sm_scale); a[1]=f2bf(f0[1]*sm_scale);
            a[2]=f2bf(f0[2]*sm_scale); a[3]=f2bf(f0[3]*sm_scale);
            a[4]=f2bf(f1[0]*sm_scale); a[5]=f2bf(f1[1]*sm_scale);
            a[6]=f2bf(f1[2]*sm_scale); a[7]=f2bf(f1[3]*sm_scale);
            afrag[t] = a;
        }
        #pragma unroll
        for (int c = 0; c < 8; c++) {
            short8 bfrag = *(const short8*)(Ksh + (c * 16 + l16) * Dc + d0);
            #pragma unroll
            for (int t = 0; t < 2; t++)
                acc[t][c] = __builtin_amdgcn_mfma_f32_16x16x32_bf16(
                    afrag[t], bfrag, acc[t][c], 0, 0, 0);
        }
    }

    // ---- mask + softmax (in place on acc) ----
    // element: query row = m0 + row_base + t*16 + quad*4 + r ; block j = c*16 + l16
    float inv_l[2][4];
    #pragma unroll
    for (int t = 0; t < 2; t++) {
        #pragma unroll
        for (int r = 0; r < 4; r++) {
            const int mg = m0 + row_base + t * 16 + quad * 4 + r;
            int nvalid = (mg + 1) >> 5;            // block j valid iff j < nvalid
            if (nvalid > NBc) nvalid = NBc;
            float mx = -1e30f;
            #pragma unroll
            for (int c = 0; c < 8; c++) {
                const int j = c * 16 + l16;
                float s = (j < nvalid) ? acc[t][c][r] : -1e30f;
                acc[t][c][r] = s;
                mx = fmaxf(mx, s);
            }
            #pragma unroll
            for (int off = 1; off < 16; off <<= 1)
                mx = fmaxf(mx, __shfl_xor(mx, off, 64));
            float lsum = 0.f;
            #pragma unroll
            for (int c = 0; c < 8; c++) {
                float s = acc[t][c][r];
                float p = (s > -1e29f) ? __expf(s - mx) : 0.f;
                acc[t][c][r] = p;
                lsum += p;
            }
            #pragma unroll
            for (int off = 1; off < 16; off <<= 1)
                lsum += __shfl_xor(lsum, off, 64);
            inv_l[t][r] = (lsum > 0.f) ? 1.f / lsum : 0.f;
        }
    }

    __syncthreads();            // everyone done reading Ksh
    // ---- write P (bf16) over K's buffer: P[row 0..127][blk 0..127] ----
    short* P = Ksh;
    #pragma unroll
    for (int t = 0; t < 2; t++)
        #pragma unroll
        for (int c = 0; c < 8; c++)
            #pragma unroll
            for (int r = 0; r < 4; r++)
                P[(row_base + t * 16 + quad * 4 + r) * NBc + c * 16 + l16] =
                    f2bf(acc[t][c][r]);
    __syncthreads();            // P visible

    // ---- O = P * V ----
    float4v oacc[2][8];
    #pragma unroll
    for (int t = 0; t < 2; t++)
        #pragma unroll
        for (int c = 0; c < 8; c++) oacc[t][c] = (float4v)0.f;

    #pragma unroll
    for (int kbi = 0; kbi < 4; kbi++) {
        const int b0 = kbi * 32 + quad * 8;
        short8 afrag[2];
        #pragma unroll
        for (int t = 0; t < 2; t++)
            afrag[t] = *(const short8*)(P + (row_base + t * 16 + l16) * NBc + b0);
        #pragma unroll
        for (int c = 0; c < 8; c++) {
            short8 bfrag = *(const short8*)(Vt + (c * 16 + l16) * NBc + b0);
            #pragma unroll
            for (int t = 0; t < 2; t++)
                oacc[t][c] = __builtin_amdgcn_mfma_f32_16x16x32_bf16(
                    afrag[t], bfrag, oacc[t][c], 0, 0, 0);
        }
    }

    // ---- epilogue: divide by l, store fp32 ----
    float* otile = out + (((size_t)(z * Hc + h)) * Sc + m0) * Dc;
    #pragma unroll
    for (int t = 0; t < 2; t++)
        #pragma unroll
        for (int r = 0; r < 4; r++) {
            const int row = row_base + t * 16 + quad * 4 + r;
            const float s = inv_l[t][r];
            #pragma unroll
            for (int c = 0; c < 8; c++)
                otile[(size_t)row * Dc + c * 16 + l16] = oacc[t][c][r] * s;
        }
}

extern "C" void kernel_launch(void* const* d_in, const int* in_sizes, int n_in,
                              void* d_out, int out_size, void* d_ws, size_t ws_size,
                              hipStream_t stream) {
    const float* q  = (const float*)d_in[0];
    const float* kb = (const float*)d_in[1];
    const float* vb = (const float*)d_in[2];
    // d_in[3] = block_ends; mask is analytic: block j valid iff j < (m+1)>>5
    float* out = (float*)d_out;
    dim3 grid(Sc / 128, Hc, Zc);
    nsa_fwd<<<grid, dim3(256), 0, stream>>>(q, kb, vb, out);
}